// Round 7
// baseline (671.669 us; speedup 1.0000x reference)
//
#include <hip/hip_runtime.h>
#include <math.h>

#define N_NODES 100000
#define N_EDGES 3200000
#define N_GRAPHS 64
#define IN_DIM 128
#define HID 64
#define BN_EPS 1e-5f

#define PSHIFT 9
#define PBS 512
#define NPB ((N_NODES + PBS - 1) / PBS)  // 196
#define PART_BLOCKS 256
#define CHUNK_E (N_EDGES / PART_BLOCKS)  // 12500

#define QBOUND 25000                 // src tile: 25000*128B = 3.2 MB (fits 4MB XCD L2)
#define AGG_BLOCKS 2048
#define NSLOT (AGG_BLOCKS * 16)      // 32768 16-lane groups
#define NSTRIP ((N_NODES + NSLOT - 1) / NSLOT)  // 4

typedef unsigned short ushort_t;

__device__ __forceinline__ float bflo(unsigned u) { return __uint_as_float(u << 16); }
__device__ __forceinline__ float bfhi(unsigned u) { return __uint_as_float(u & 0xFFFF0000u); }
__device__ __forceinline__ unsigned f2bf(float f) {  // RNE
  unsigned u = __float_as_uint(f);
  return (u + 0x7FFFu + ((u >> 16) & 1u)) >> 16;
}

// ---------------- CSR build: two-level bucket sort, src-quartile segmented ----------------

__global__ __launch_bounds__(256) void ghist_k(const int* __restrict__ ei,
                                               int* __restrict__ gh) {
  __shared__ int h[NPB];
  for (int i = threadIdx.x; i < NPB; i += 256) h[i] = 0;
  __syncthreads();
  int stride = gridDim.x * 256;
  for (int e = blockIdx.x * 256 + threadIdx.x; e < N_EDGES; e += stride)
    atomicAdd(&h[ei[N_EDGES + e] >> PSHIFT], 1);
  __syncthreads();
  for (int i = threadIdx.x; i < NPB; i += 256) {
    int v = h[i];
    if (v) atomicAdd(&gh[i], v);
  }
}

__global__ __launch_bounds__(256) void gscan_k(const int* __restrict__ gh,
                                               int* __restrict__ boff,
                                               int* __restrict__ gcur) {
  __shared__ int sa[256], sb[256];
  int t = threadIdx.x;
  int v = (t < NPB) ? gh[t] : 0;
  sa[t] = v;
  __syncthreads();
  int* src = sa; int* dst = sb;
  for (int o = 1; o < 256; o <<= 1) {
    dst[t] = src[t] + ((t >= o) ? src[t - o] : 0);
    __syncthreads();
    int* tmp = src; src = dst; dst = tmp;
  }
  if (t < NPB) {
    int excl = src[t] - v;
    boff[t] = excl;
    gcur[t] = excl;
    if (t == NPB - 1) boff[NPB] = src[t];
  }
}

__global__ __launch_bounds__(512) void part_k(const int* __restrict__ ei,
                                              int* __restrict__ gcur,
                                              unsigned* __restrict__ tmp) {
  __shared__ int lh[NPB];
  __shared__ int lcur[NPB];
  int t = threadIdx.x;
  for (int i = t; i < NPB; i += 512) lh[i] = 0;
  __syncthreads();
  int c0 = blockIdx.x * CHUNK_E;
  int c1 = c0 + CHUNK_E;
  for (int e = c0 + t; e < c1; e += 512)
    atomicAdd(&lh[ei[N_EDGES + e] >> PSHIFT], 1);
  __syncthreads();
  for (int i = t; i < NPB; i += 512) {
    int v = lh[i];
    lcur[i] = v ? atomicAdd(&gcur[i], v) : 0;
  }
  __syncthreads();
  for (int e = c0 + t; e < c1; e += 512) {
    int dst = ei[N_EDGES + e];
    int src = ei[e];
    int b = dst >> PSHIFT;
    int p = atomicAdd(&lcur[b], 1);
    tmp[p] = ((unsigned)(dst & (PBS - 1)) << 17) | (unsigned)src;
  }
}

// fused per-bucket: histogram per (node, src-quartile) -> rp4/dinv -> place
__global__ __launch_bounds__(512) void bwork_k(
    const unsigned* __restrict__ tmp, const int* __restrict__ boff,
    int* __restrict__ rp4, float* __restrict__ dinv, int* __restrict__ csr) {
  int b = blockIdx.x;
  int base = boff[b], end = boff[b + 1];
  int t = threadIdx.x;
  __shared__ int cnt[PBS * 4];
  __shared__ int cur[PBS * 4];
  __shared__ int sa[PBS], sb[PBS];
  for (int i = t; i < PBS * 4; i += 512) cnt[i] = 0;
  __syncthreads();
  for (int i = base + t; i < end; i += 512) {
    unsigned u = tmp[i];
    int nl = u >> 17;
    int src = u & 0x1FFFF;
    int qq = (src >= QBOUND) + (src >= 2 * QBOUND) + (src >= 3 * QBOUND);
    atomicAdd(&cnt[nl * 4 + qq], 1);
  }
  __syncthreads();
  int c0 = cnt[t * 4], c1 = cnt[t * 4 + 1], c2 = cnt[t * 4 + 2], c3 = cnt[t * 4 + 3];
  int tsum = c0 + c1 + c2 + c3;
  sa[t] = tsum;
  __syncthreads();
  int* src_ = sa; int* dst_ = sb;
  for (int o = 1; o < PBS; o <<= 1) {
    dst_[t] = src_[t] + ((t >= o) ? src_[t - o] : 0);
    __syncthreads();
    int* z = src_; src_ = dst_; dst_ = z;
  }
  int nb = src_[t] - tsum;  // exclusive node base within bucket
  int o0 = nb, o1 = nb + c0, o2 = nb + c0 + c1, o3 = nb + c0 + c1 + c2;
  cur[t * 4] = o0; cur[t * 4 + 1] = o1; cur[t * 4 + 2] = o2; cur[t * 4 + 3] = o3;
  int n = b * PBS + t;
  if (n < N_NODES) {
    rp4[4 * n] = base + o0;
    rp4[4 * n + 1] = base + o1;
    rp4[4 * n + 2] = base + o2;
    rp4[4 * n + 3] = base + o3;
    dinv[n] = rsqrtf((float)(tsum + 1));  // +1 self loop
    if (n == N_NODES - 1) rp4[4 * N_NODES] = base + nb + tsum;
  }
  __syncthreads();
  for (int i = base + t; i < end; i += 512) {
    unsigned u = tmp[i];
    int nl = u >> 17;
    int src = u & 0x1FFFF;
    int qq = (src >= QBOUND) + (src >= 2 * QBOUND) + (src >= 3 * QBOUND);
    int p = atomicAdd(&cur[nl * 4 + qq], 1);
    csr[base + p] = src << 7;  // byte offset into bf16 hs
  }
}

// ---------------- GEMM: hs[n][c] = dinv[n] * (BN(X)[n] @ W)[c] -> bf16 ----------------

template <int K, bool APPLY, bool RELU>
__global__ __launch_bounds__(256) void gemm_k(
    const float* __restrict__ X, const float* __restrict__ W,
    const float* __restrict__ scale, const float* __restrict__ shift,
    const float* __restrict__ dinv, ushort_t* __restrict__ out, int nrows) {
  constexpr int WROW = K + 1;
  __shared__ float wt[64 * WROW];   // wt[c][k]  (W transposed)
  __shared__ float xs[64 * 68];     // xs[r][k]
  const int tid = threadIdx.x;
  const int tc = tid & 15;
  const int tr = tid >> 4;

  for (int idx = tid; idx < K * 64; idx += 256) {
    int k = idx >> 6, c = idx & 63;
    wt[c * WROW + k] = W[idx];
  }

  const int rowbase = blockIdx.x * 64;
  float acc[4][4] = {};

  for (int kc = 0; kc < K; kc += 64) {
    __syncthreads();
    {
      const int kq = tid & 15;
      const int rr = tid >> 4;
#pragma unroll
      for (int p = 0; p < 4; ++p) {
        int r = rr + p * 16;
        int grow = rowbase + r;
        float4 v = make_float4(0.f, 0.f, 0.f, 0.f);
        if (grow < nrows) v = *(const float4*)(X + (size_t)grow * K + kc + kq * 4);
        if (APPLY) {
          int kg = kc + kq * 4;
          float4 sc = *(const float4*)(scale + kg);
          float4 sh = *(const float4*)(shift + kg);
          v.x = v.x * sc.x + sh.x;
          v.y = v.y * sc.y + sh.y;
          v.z = v.z * sc.z + sh.z;
          v.w = v.w * sc.w + sh.w;
          if (RELU) {
            v.x = fmaxf(v.x, 0.f); v.y = fmaxf(v.y, 0.f);
            v.z = fmaxf(v.z, 0.f); v.w = fmaxf(v.w, 0.f);
          }
        }
        *(float4*)(xs + r * 68 + kq * 4) = v;
      }
    }
    __syncthreads();
#pragma unroll 4
    for (int k0 = 0; k0 < 64; k0 += 4) {
      float4 xv[4], wv[4];
#pragma unroll
      for (int i = 0; i < 4; ++i)
        xv[i] = *(const float4*)(xs + (tr * 4 + i) * 68 + k0);
#pragma unroll
      for (int j = 0; j < 4; ++j)
        wv[j] = *(const float4*)(wt + (4 * tc + j) * WROW + kc + k0);
#pragma unroll
      for (int i = 0; i < 4; ++i)
#pragma unroll
        for (int j = 0; j < 4; ++j)
          acc[i][j] += xv[i].x * wv[j].x + xv[i].y * wv[j].y +
                       xv[i].z * wv[j].z + xv[i].w * wv[j].w;
    }
  }

  char* ob = (char*)out;
#pragma unroll
  for (int i = 0; i < 4; ++i) {
    int grow = rowbase + tr * 4 + i;
    if (grow < nrows) {
      float dn = dinv[grow];
      uint2 o;
      o.x = f2bf(acc[i][0] * dn) | (f2bf(acc[i][1] * dn) << 16);
      o.y = f2bf(acc[i][2] * dn) | (f2bf(acc[i][3] * dn) << 16);
      *(uint2*)(ob + (size_t)grow * 128 + tc * 8) = o;
    }
  }
}

// ---------------- src-tiled aggregation (no grid sync) + fused BN stats ----------------
// out[d] = dinv[d] * (sum_src hs[src] + hs[d]) + bias. 4 phases; in phase p
// every block gathers only from rows [25000p, 25000(p+1)) = 3.2 MB. Blocks
// start together and per-phase work is uniform, so phases stay softly
// aligned -> gathers mostly L2-resident. Correctness never depends on
// alignment (hs is read-only; accumulators in registers).

__global__ __launch_bounds__(256) void agg_k(
    const ushort_t* __restrict__ hs, const float* __restrict__ dinv,
    const int* __restrict__ rp4, const int* __restrict__ csr,
    const float* __restrict__ bias, float* __restrict__ out,
    float* __restrict__ sums) {
  const int tid = threadIdx.x;
  const int w = tid >> 6;
  const int lane = tid & 63;
  const int g = lane >> 4;
  const int q = lane & 15;
  const int slot = blockIdx.x * 16 + w * 4 + g;
  const char* hb = (const char*)hs;

  float4 acc[NSTRIP];
#pragma unroll
  for (int k = 0; k < NSTRIP; ++k) {
    int n = slot + k * NSLOT;
    if (n < N_NODES) {
      uint2 u = *(const uint2*)(hb + ((size_t)n << 7) + (q << 3));  // self
      acc[k] = make_float4(bflo(u.x), bfhi(u.x), bflo(u.y), bfhi(u.y));
    } else {
      acc[k] = make_float4(0.f, 0.f, 0.f, 0.f);
    }
  }

  for (int p = 0; p < 4; ++p) {
#pragma unroll
    for (int k = 0; k < NSTRIP; ++k) {
      int n = slot + k * NSLOT;
      if (n < N_NODES) {
        int r0 = rp4[4 * n + p];
        int r1 = rp4[4 * n + p + 1];
        float4 a = acc[k];
        int j = r0;
        for (; j + 4 <= r1; j += 4) {
          int e0 = csr[j], e1 = csr[j + 1], e2 = csr[j + 2], e3 = csr[j + 3];
          uint2 v0 = *(const uint2*)(hb + (size_t)(unsigned)e0 + (q << 3));
          uint2 v1 = *(const uint2*)(hb + (size_t)(unsigned)e1 + (q << 3));
          uint2 v2 = *(const uint2*)(hb + (size_t)(unsigned)e2 + (q << 3));
          uint2 v3 = *(const uint2*)(hb + (size_t)(unsigned)e3 + (q << 3));
          a.x += (bflo(v0.x) + bflo(v1.x)) + (bflo(v2.x) + bflo(v3.x));
          a.y += (bfhi(v0.x) + bfhi(v1.x)) + (bfhi(v2.x) + bfhi(v3.x));
          a.z += (bflo(v0.y) + bflo(v1.y)) + (bflo(v2.y) + bflo(v3.y));
          a.w += (bfhi(v0.y) + bfhi(v1.y)) + (bfhi(v2.y) + bfhi(v3.y));
        }
        for (; j < r1; ++j) {
          int e = csr[j];
          uint2 v = *(const uint2*)(hb + (size_t)(unsigned)e + (q << 3));
          a.x += bflo(v.x); a.y += bfhi(v.x);
          a.z += bflo(v.y); a.w += bfhi(v.y);
        }
        acc[k] = a;
      }
    }
  }

  // finalize: *dinv, +bias, write, BN partial stats
  float4 bval = *(const float4*)(bias + q * 4);
  float4 s = make_float4(0.f, 0.f, 0.f, 0.f);
  float4 s2 = make_float4(0.f, 0.f, 0.f, 0.f);
#pragma unroll
  for (int k = 0; k < NSTRIP; ++k) {
    int n = slot + k * NSLOT;
    if (n < N_NODES) {
      float dn = dinv[n];
      float4 a;
      a.x = acc[k].x * dn + bval.x;
      a.y = acc[k].y * dn + bval.y;
      a.z = acc[k].z * dn + bval.z;
      a.w = acc[k].w * dn + bval.w;
      *(float4*)(out + ((size_t)n << 6) + q * 4) = a;
      s.x += a.x; s.y += a.y; s.z += a.z; s.w += a.w;
      s2.x += a.x * a.x; s2.y += a.y * a.y;
      s2.z += a.z * a.z; s2.w += a.w * a.w;
    }
  }

  __shared__ float rs[16][64];
  __shared__ float rs2[16][64];
  *(float4*)(&rs[w * 4 + g][q * 4]) = s;
  *(float4*)(&rs2[w * 4 + g][q * 4]) = s2;
  __syncthreads();
  int c = tid & 63;
  int r0 = tid >> 6;
  float a = rs[r0][c] + rs[r0 + 4][c] + rs[r0 + 8][c] + rs[r0 + 12][c];
  float a2 = rs2[r0][c] + rs2[r0 + 4][c] + rs2[r0 + 8][c] + rs2[r0 + 12][c];
  __syncthreads();
  rs[r0][c] = a;
  rs2[r0][c] = a2;
  __syncthreads();
  if (r0 == 0) {
    atomicAdd(&sums[c], rs[0][c] + rs[1][c] + rs[2][c] + rs[3][c]);
    atomicAdd(&sums[64 + c], rs2[0][c] + rs2[1][c] + rs2[2][c] + rs2[3][c]);
  }
}

__global__ void bnfinal_k(const float* __restrict__ sums,
                          const float* __restrict__ gamma, const float* __restrict__ beta,
                          float* __restrict__ scale, float* __restrict__ shift) {
  int c = threadIdx.x;  // 64 threads
  float mean = sums[c] / (float)N_NODES;
  float var = sums[64 + c] / (float)N_NODES - mean * mean;
  float sc = gamma[c] * rsqrtf(var + BN_EPS);
  scale[c] = sc;
  shift[c] = beta[c] - mean * sc;
}

// ---------------- pooling (batch is sorted) ----------------

#define POOL_CHUNK 32
__global__ __launch_bounds__(64) void pool_k(
    const float* __restrict__ h, const float* __restrict__ scale,
    const float* __restrict__ shift, const int* __restrict__ batch,
    float* __restrict__ psum, float* __restrict__ pcnt) {
  int lane = threadIdx.x;
  int start = blockIdx.x * POOL_CHUNK;
  if (start >= N_NODES) return;
  int end = min(start + POOL_CHUNK, N_NODES);
  float sc = scale[lane], sh = shift[lane];
  float acc = 0.f, cnt = 0.f;
  int cur = batch[start];
  for (int n = start; n < end; ++n) {
    int g = batch[n];
    if (g != cur) {
      atomicAdd(&psum[cur * 64 + lane], acc);
      if (lane == 0) atomicAdd(&pcnt[cur], cnt);
      acc = 0.f; cnt = 0.f; cur = g;
    }
    acc += h[(size_t)n * 64 + lane] * sc + sh;
    cnt += 1.f;
  }
  atomicAdd(&psum[cur * 64 + lane], acc);
  if (lane == 0) atomicAdd(&pcnt[cur], cnt);
}

// ---------------- centroid classifier ----------------

__global__ void classify_k(const float* __restrict__ psum, const float* __restrict__ pcnt,
                           const float* __restrict__ cg_, const float* __restrict__ cm,
                           const float* __restrict__ temp, float* __restrict__ out) {
  int g = blockIdx.x;
  int t = threadIdx.x;
  __shared__ float emb[64];
  __shared__ float dist[208];
  if (t < 64) emb[t] = psum[g * 64 + t] / fmaxf(pcnt[g], 1.0f);
  __syncthreads();
  if (t < 197) {
    const float* C = (t < 5) ? (cg_ + t * 64) : (cm + (t - 5) * 64);
    float d = 0.f;
#pragma unroll 8
    for (int k = 0; k < 64; ++k) {
      float df = emb[k] - C[k];
      d += df * df;
    }
    dist[t] = d;
  }
  __syncthreads();
  float tv = temp[0];
  if (t == 64) {
    float m = dist[0];
    for (int j = 1; j < 5; ++j) m = fminf(m, dist[j]);
    out[g * 65] = -m / tv;
  }
  if (t < 64) {
    float m = fminf(dist[5 + t * 3], fminf(dist[5 + t * 3 + 1], dist[5 + t * 3 + 2]));
    out[g * 65 + 1 + t] = -m / tv;
  }
}

// ---------------- launch ----------------

extern "C" void kernel_launch(void* const* d_in, const int* in_sizes, int n_in,
                              void* d_out, int out_size, void* d_ws, size_t ws_size,
                              hipStream_t stream) {
  const float* x   = (const float*)d_in[0];
  const int* ei    = (const int*)d_in[1];
  const int* batch = (const int*)d_in[2];
  const float* W1 = (const float*)d_in[3];  const float* b1 = (const float*)d_in[4];
  const float* g1 = (const float*)d_in[5];  const float* be1 = (const float*)d_in[6];
  const float* W2 = (const float*)d_in[7];  const float* b2 = (const float*)d_in[8];
  const float* g2 = (const float*)d_in[9];  const float* be2 = (const float*)d_in[10];
  const float* W3 = (const float*)d_in[11]; const float* b3 = (const float*)d_in[12];
  const float* g3 = (const float*)d_in[13]; const float* be3 = (const float*)d_in[14];
  const float* cg_ = (const float*)d_in[15];
  const float* cm = (const float*)d_in[16];
  const float* temp = (const float*)d_in[17];
  float* out = (float*)d_out;

  char* ws = (char*)d_ws;
  size_t off = 0;
  auto alloc = [&](size_t bytes) -> void* {
    void* p = ws + off;
    off = (off + bytes + 255) & ~(size_t)255;
    return p;
  };
  int* gh        = (int*)alloc((size_t)NPB * 4);
  int* boff      = (int*)alloc((size_t)(NPB + 1) * 4);
  int* gcur      = (int*)alloc((size_t)NPB * 4);
  unsigned* tmp  = (unsigned*)alloc((size_t)N_EDGES * 4);
  int* csr       = (int*)alloc((size_t)N_EDGES * 4);
  int* rp4       = (int*)alloc((size_t)(4 * N_NODES + 1) * 4);
  float* dinv    = (float*)alloc((size_t)N_NODES * 4);
  ushort_t* hA   = (ushort_t*)alloc((size_t)N_NODES * 64 * 2);  // bf16 hs
  float* hB      = (float*)alloc((size_t)N_NODES * 64 * 4);
  float* sumsAll = (float*)alloc(3 * 128 * 4);
  float* scale   = (float*)alloc(64 * 4);
  float* shift   = (float*)alloc(64 * 4);
  float* psum    = (float*)alloc(64 * 64 * 4);
  float* pcnt    = (float*)alloc(64 * 4);

  hipMemsetAsync(gh, 0, (size_t)NPB * 4, stream);
  hipMemsetAsync(sumsAll, 0, 3 * 128 * 4, stream);
  hipMemsetAsync(psum, 0, 64 * 64 * 4, stream);
  hipMemsetAsync(pcnt, 0, 64 * 4, stream);

  const int NB_GEMM = (N_NODES + 63) / 64;   // 1563
  const int NB_POOL = (N_NODES + POOL_CHUNK - 1) / POOL_CHUNK;

  // CSR build
  ghist_k<<<512, 256, 0, stream>>>(ei, gh);
  gscan_k<<<1, 256, 0, stream>>>(gh, boff, gcur);
  part_k<<<PART_BLOCKS, 512, 0, stream>>>(ei, gcur, tmp);
  bwork_k<<<NPB, 512, 0, stream>>>(tmp, boff, rp4, dinv, csr);

  // layer 1
  gemm_k<IN_DIM, false, false><<<NB_GEMM, 256, 0, stream>>>(x, W1, nullptr, nullptr, dinv, hA, N_NODES);
  agg_k<<<AGG_BLOCKS, 256, 0, stream>>>(hA, dinv, rp4, csr, b1, hB, sumsAll);
  bnfinal_k<<<1, 64, 0, stream>>>(sumsAll, g1, be1, scale, shift);

  // layer 2
  gemm_k<HID, true, true><<<NB_GEMM, 256, 0, stream>>>(hB, W2, scale, shift, dinv, hA, N_NODES);
  agg_k<<<AGG_BLOCKS, 256, 0, stream>>>(hA, dinv, rp4, csr, b2, hB, sumsAll + 128);
  bnfinal_k<<<1, 64, 0, stream>>>(sumsAll + 128, g2, be2, scale, shift);

  // layer 3
  gemm_k<HID, true, true><<<NB_GEMM, 256, 0, stream>>>(hB, W3, scale, shift, dinv, hA, N_NODES);
  agg_k<<<AGG_BLOCKS, 256, 0, stream>>>(hA, dinv, rp4, csr, b3, hB, sumsAll + 256);
  bnfinal_k<<<1, 64, 0, stream>>>(sumsAll + 256, g3, be3, scale, shift);

  // pool (BN3 applied here) + classify
  pool_k<<<NB_POOL, 64, 0, stream>>>(hB, scale, shift, batch, psum, pcnt);
  classify_k<<<N_GRAPHS, 256, 0, stream>>>(psum, pcnt, cg_, cm, temp, out);
}